// Round 3
// baseline (10192.650 us; speedup 1.0000x reference)
//
#include <hip/hip_runtime.h>
#include <hip/hip_bf16.h>
#include <math.h>

typedef __hip_bfloat16 bf16;

#define T_TOK 2048
#define HID 2048
#define NH 16
#define D_NOPE 128
#define D_ROPE 64
#define D_QK 192
#define D_V 128
#define Q_LORA 1536
#define KV_LORA 512
#define QKV_A_COLS (Q_LORA + KV_LORA + D_ROPE)   // 2112
#define SCALING 0.07216878364870323f             // 192^-0.5

__device__ inline float cvt(float x) { return x; }
__device__ inline float cvt(bf16 x) { return __bfloat162float(x); }
__device__ inline void stc(float* p, float v) { *p = v; }
__device__ inline void stc(bf16* p, float v) { *p = __float2bfloat16(v); }

// ---------------------------------------------------------------------------
// LDS-tiled 16x16 GEMM, fp32 accumulate, optional fused per-row scale (RMSNorm
// rstd) and per-col gain g on the A operand:
//   C[row, col] = sum_k (A[row, a_off+k] * rs[row] * g[k]) * B[k, col]
// N, K multiples of 16.
// ---------------------------------------------------------------------------
template <typename TA, typename TC>
__global__ void gemm16(const TA* __restrict__ A, int lda, int a_off,
                       const float* __restrict__ rscale,
                       const float* __restrict__ g,
                       const float* __restrict__ B, TC* __restrict__ C,
                       int N, int K) {
    __shared__ float As[16][17];
    __shared__ float Bs[16][17];
    int tx = threadIdx.x, ty = threadIdx.y;
    int col = blockIdx.x * 16 + tx;
    int row = blockIdx.y * 16 + ty;
    float rs = rscale ? rscale[row] : 1.f;
    float acc = 0.f;
    for (int k0 = 0; k0 < K; k0 += 16) {
        float a = cvt(A[(size_t)row * lda + a_off + k0 + tx]);
        if (g) a *= g[k0 + tx];
        As[ty][tx] = a * rs;
        Bs[ty][tx] = B[(size_t)(k0 + ty) * N + col];
        __syncthreads();
#pragma unroll
        for (int kk = 0; kk < 16; kk++) acc += As[ty][kk] * Bs[kk][tx];
        __syncthreads();
    }
    stc(&C[(size_t)row * N + col], acc);
}

// ---------------------------------------------------------------------------
// Per-row RMSNorm scales for both latents in one pass.
// rq[row]  = rsqrt(mean(qkv_a[row, 0:1536]^2)    + eps)
// rkv[row] = rsqrt(mean(qkv_a[row, 1536:2048]^2) + eps)
// ---------------------------------------------------------------------------
__global__ void rms_scales(const float* __restrict__ qkv_a,
                           float* __restrict__ rq, float* __restrict__ rkv) {
    int row = blockIdx.x, tid = threadIdx.x;
    const float* x = qkv_a + (size_t)row * QKV_A_COLS;
    __shared__ float red[256];
    float ss = 0.f;
    for (int c = tid; c < Q_LORA; c += 256) { float v = x[c]; ss += v * v; }
    red[tid] = ss;
    __syncthreads();
    for (int o = 128; o > 0; o >>= 1) {
        if (tid < o) red[tid] += red[tid + o];
        __syncthreads();
    }
    if (tid == 0) rq[row] = rsqrtf(red[0] / (float)Q_LORA + 1e-6f);
    __syncthreads();
    ss = 0.f;
    for (int c = Q_LORA + tid; c < Q_LORA + KV_LORA; c += 256) {
        float v = x[c]; ss += v * v;
    }
    red[tid] = ss;
    __syncthreads();
    for (int o = 128; o > 0; o >>= 1) {
        if (tid < o) red[tid] += red[tid + o];
        __syncthreads();
    }
    if (tid == 0) rkv[row] = rsqrtf(red[0] / (float)KV_LORA + 1e-6f);
}

// ---------------------------------------------------------------------------
// RoPE for shared k_pe: read qkv_a[:, 2048:2112] (fp32), write kpe [T,64] fp32
// ---------------------------------------------------------------------------
__global__ void rope_kpe_kernel(const float* __restrict__ qkv_a,
                                const int* __restrict__ pos,
                                float* __restrict__ kpe) {
    int idx = blockIdx.x * blockDim.x + threadIdx.x;
    if (idx >= T_TOK * 32) return;
    int t = idx >> 5, i = idx & 31;
    double inv = pow(10000.0, -(double)(2 * i) / 64.0);
    double fd = (double)pos[t] * inv;
    float c = (float)cos(fd), s = (float)sin(fd);
    const float* src = qkv_a + (size_t)t * QKV_A_COLS + Q_LORA + KV_LORA;
    float x1 = src[2 * i], x2 = src[2 * i + 1];
    kpe[t * 64 + 2 * i] = x1 * c - x2 * s;
    kpe[t * 64 + 2 * i + 1] = x1 * s + x2 * c;
}

// ---------------------------------------------------------------------------
// RoPE in-place on q_pe portion of q buffer [T, NH*192] (bf16), dims 128..191
// ---------------------------------------------------------------------------
__global__ void rope_q_kernel(bf16* __restrict__ q, const int* __restrict__ pos) {
    int idx = blockIdx.x * blockDim.x + threadIdx.x;  // t*NH*32 + h*32 + i
    if (idx >= T_TOK * NH * 32) return;
    int i = idx & 31;
    int h = (idx >> 5) & (NH - 1);
    int t = idx >> 9;
    double inv = pow(10000.0, -(double)(2 * i) / 64.0);
    double fd = (double)pos[t] * inv;
    float c = (float)cos(fd), s = (float)sin(fd);
    bf16* base = q + (size_t)t * (NH * D_QK) + h * D_QK + D_NOPE;
    float x1 = cvt(base[2 * i]), x2 = cvt(base[2 * i + 1]);
    stc(&base[2 * i], x1 * c - x2 * s);
    stc(&base[2 * i + 1], x1 * s + x2 * c);
}

// ---------------------------------------------------------------------------
// Causal attention, one block = (query t, head h), two-pass softmax in LDS.
// q  : [T, NH*192]  bf16 (rope applied)
// kv : [T, NH*256]  bf16 (k_nope 0:128, v 128:256 per head)
// kpe: [T, 64]      fp32 (rope applied, shared across heads)
// out: [T, NH*128]  fp32
// ---------------------------------------------------------------------------
__global__ void attn_kernel(const bf16* __restrict__ q,
                            const bf16* __restrict__ kv,
                            const float* __restrict__ kpe,
                            float* __restrict__ out) {
    int t = blockIdx.x;
    int h = blockIdx.y;
    int tid = threadIdx.x;
    __shared__ float qs[D_QK];
    __shared__ float sc[T_TOK];
    __shared__ float red[256];

    for (int d = tid; d < D_QK; d += 256)
        qs[d] = cvt(q[(size_t)t * (NH * D_QK) + h * D_QK + d]);
    __syncthreads();

    // phase 1: scores + local max
    float lmax = -1e30f;
    for (int s = tid; s <= t; s += 256) {
        const bf16* krow = kv + (size_t)s * (NH * 256) + h * 256;
        const float* pe = kpe + (size_t)s * 64;
        float dot = 0.f;
#pragma unroll 4
        for (int d = 0; d < D_NOPE; d++) dot += qs[d] * cvt(krow[d]);
#pragma unroll 4
        for (int j = 0; j < D_ROPE; j++) dot += qs[D_NOPE + j] * pe[j];
        dot *= SCALING;
        sc[s] = dot;
        lmax = fmaxf(lmax, dot);
    }
    red[tid] = lmax;
    __syncthreads();
    for (int o = 128; o > 0; o >>= 1) {
        if (tid < o) red[tid] = fmaxf(red[tid], red[tid + o]);
        __syncthreads();
    }
    float m = red[0];
    __syncthreads();

    // phase 2: exp + sum
    float lsum = 0.f;
    for (int s = tid; s <= t; s += 256) {
        float e = expf(sc[s] - m);
        sc[s] = e;
        lsum += e;
    }
    red[tid] = lsum;
    __syncthreads();
    for (int o = 128; o > 0; o >>= 1) {
        if (tid < o) red[tid] += red[tid + o];
        __syncthreads();
    }
    float inv_sum = 1.f / red[0];
    __syncthreads();

    // phase 3: weighted V sum, threads 0..127 each own one output dim
    if (tid < D_V) {
        float acc = 0.f;
        for (int s = 0; s <= t; s++)
            acc += sc[s] * cvt(kv[(size_t)s * (NH * 256) + h * 256 + D_NOPE + tid]);
        out[(size_t)t * (NH * D_V) + h * D_V + tid] = acc * inv_sum;
    }
}

// ---------------------------------------------------------------------------
extern "C" void kernel_launch(void* const* d_in, const int* in_sizes, int n_in,
                              void* d_out, int out_size, void* d_ws, size_t ws_size,
                              hipStream_t stream) {
    // Reference setup_inputs(): ALL float arrays are jnp.float32; positions int32.
    const float* hidden = (const float*)d_in[0];
    const int* positions = (const int*)d_in[1];
    const float* w_qkv_a = (const float*)d_in[2];
    const float* g_q = (const float*)d_in[3];
    const float* w_q_b = (const float*)d_in[4];
    const float* g_kv = (const float*)d_in[5];
    const float* w_kv_b = (const float*)d_in[6];
    const float* w_o = (const float*)d_in[7];
    float* out = (float*)d_out;   // reference output dtype: float32

    // workspace layout (~47 MB total):
    //   qkv_a  fp32 [2048,2112] 17.3 MB  (dead after steps 3/4/6)
    //   attn_o fp32 [2048,2048] 16.8 MB  -- ALIASED over qkv_a
    //   kpe    fp32 [2048,64]
    //   rq,rkv fp32 [2048] each
    //   qbuf   bf16 [2048,3072] 12.6 MB
    //   kvbuf  bf16 [2048,4096] 16.8 MB
    float* qkv_a = (float*)d_ws;
    float* attn_o = qkv_a;  // alias: qkv_a is dead by the time attn writes
    float* kpe = qkv_a + (size_t)T_TOK * QKV_A_COLS;
    float* rq = kpe + (size_t)T_TOK * 64;
    float* rkv = rq + T_TOK;
    bf16* qbuf = (bf16*)(rkv + T_TOK);
    bf16* kvbuf = qbuf + (size_t)T_TOK * (NH * D_QK);

    dim3 blk(16, 16);

    // 1. qkv_a = hidden @ w_qkv_a   [2048x2112], K=2048
    gemm16<float, float><<<dim3(QKV_A_COLS / 16, T_TOK / 16), blk, 0, stream>>>(
        hidden, HID, 0, nullptr, nullptr, w_qkv_a, qkv_a, QKV_A_COLS, HID);

    // 2. per-row rmsnorm scales for q and kv latents
    rms_scales<<<T_TOK, 256, 0, stream>>>(qkv_a, rq, rkv);

    // 3. rope k_pe
    rope_kpe_kernel<<<(T_TOK * 32 + 255) / 256, 256, 0, stream>>>(qkv_a, positions, kpe);

    // 4. q = rmsnorm(q_lat) @ w_q_b   [2048x3072], K=1536  (norm fused in A-load)
    gemm16<float, bf16><<<dim3((NH * D_QK) / 16, T_TOK / 16), blk, 0, stream>>>(
        qkv_a, QKV_A_COLS, 0, rq, g_q, w_q_b, qbuf, NH * D_QK, Q_LORA);

    // 5. rope q_pe (in place, bf16)
    rope_q_kernel<<<(T_TOK * NH * 32 + 255) / 256, 256, 0, stream>>>(qbuf, positions);

    // 6. kv = rmsnorm(kv_lat) @ w_kv_b   [2048x4096], K=512
    gemm16<float, bf16><<<dim3((NH * 256) / 16, T_TOK / 16), blk, 0, stream>>>(
        qkv_a, QKV_A_COLS, Q_LORA, rkv, g_kv, w_kv_b, kvbuf, NH * 256, KV_LORA);

    // 7. attention (writes attn_o which aliases the now-dead qkv_a)
    attn_kernel<<<dim3(T_TOK, NH), 256, 0, stream>>>(qbuf, kvbuf, kpe, attn_o);

    // 8. out = attn_o @ w_o   [2048x2048], K=2048
    gemm16<float, float><<<dim3(HID / 16, T_TOK / 16), blk, 0, stream>>>(
        attn_o, NH * D_V, 0, nullptr, nullptr, w_o, out, HID, NH * D_V);
}

// Round 4
// 500.977 us; speedup vs baseline: 20.3456x; 20.3456x over previous
//
#include <hip/hip_runtime.h>
#include <hip/hip_bf16.h>
#include <math.h>

typedef __bf16 bf16_t;
typedef __bf16 bf16x8 __attribute__((ext_vector_type(8)));
typedef float floatx4 __attribute__((ext_vector_type(4)));

#define T_TOK 2048
#define HID 2048
#define NH 16
#define D_NOPE 128
#define D_ROPE 64
#define D_QK 192
#define D_V 128
#define Q_LORA 1536
#define KV_LORA 512
#define QKV_N 2112            // 1536+512+64
#define QKV_NPAD 2176         // padded to 17*128
#define SCALING 0.07216878364870323f
#define LOG2E 1.442695041f

#define MFMA_BF16(a, b, c) __builtin_amdgcn_mfma_f32_16x16x32_bf16(a, b, c, 0, 0, 0)

// async 16B global->LDS (verified m97 pattern; LDS dest must be lane-linear)
__device__ __forceinline__ void gload16(const void* g, void* l) {
    __builtin_amdgcn_global_load_lds(
        (const __attribute__((address_space(1))) unsigned int*)g,
        (__attribute__((address_space(3))) unsigned int*)l, 16, 0, 0);
}

// ---------------------------------------------------------------------------
// m97-style MFMA GEMM: C[M,N] = A[M,K] * Bt[N,K]^T, 128x128 tile, BK=32.
// A,Bt bf16 row-major. MODE 0: store fp32 C. MODE 1: store bf16 C.
// MODE 2 (kv-split): col=h*256+d -> d<128: knope[h][row][d]; else vtmp[row][h*128+d-128]
// Verified lane maps (learn_hip m89/m91/m92/m97):
//   A-frag lane l: A[m=l&15][k=(l>>4)*8+j]; B-frag: B[k=(l>>4)*8+j][n=l&15] (Bt row n)
//   D lane l reg r: D[row=(l>>4)*4+r][col=l&15]
// ---------------------------------------------------------------------------
template <int MODE>
__global__ __launch_bounds__(256) void gemm_mfma(
    const bf16_t* __restrict__ A, const bf16_t* __restrict__ Bt,
    float* __restrict__ Cf, bf16_t* __restrict__ Cb,
    bf16_t* __restrict__ knope, bf16_t* __restrict__ vtmp,
    int M, int N, int K)
{
    __shared__ __align__(16) bf16_t As[128 * 32];
    __shared__ __align__(16) bf16_t Bs[128 * 32];
    const int tid = threadIdx.x;
    const int lane = tid & 63;
    const int w = tid >> 6;
    const int wm = w >> 1, wn = w & 1;
    const int m0 = blockIdx.y * 128, n0 = blockIdx.x * 128;
    const int l15 = lane & 15, quad = lane >> 4;

    floatx4 acc[4][4] = {};

    for (int k0 = 0; k0 < K; k0 += 32) {
#pragma unroll
        for (int it = 0; it < 2; ++it) {
            int slot = it * 256 + tid;
            int row = slot >> 2, cb = (slot & 3) * 16;
            gload16((const char*)(A + (size_t)(m0 + row) * K + k0) + cb,
                    (char*)As + slot * 16);
            gload16((const char*)(Bt + (size_t)(n0 + row) * K + k0) + cb,
                    (char*)Bs + slot * 16);
        }
        __syncthreads();
        bf16x8 af[4], bfr[4];
#pragma unroll
        for (int mi = 0; mi < 4; ++mi)
            af[mi] = *(const bf16x8*)(As + (wm * 64 + mi * 16 + l15) * 32 + quad * 8);
#pragma unroll
        for (int ni = 0; ni < 4; ++ni)
            bfr[ni] = *(const bf16x8*)(Bs + (wn * 64 + ni * 16 + l15) * 32 + quad * 8);
#pragma unroll
        for (int mi = 0; mi < 4; ++mi)
#pragma unroll
            for (int ni = 0; ni < 4; ++ni)
                acc[mi][ni] = MFMA_BF16(af[mi], bfr[ni], acc[mi][ni]);
        __syncthreads();
    }

#pragma unroll
    for (int mi = 0; mi < 4; ++mi)
#pragma unroll
        for (int ni = 0; ni < 4; ++ni)
#pragma unroll
            for (int r = 0; r < 4; ++r) {
                int row = m0 + wm * 64 + mi * 16 + quad * 4 + r;
                int col = n0 + wn * 64 + ni * 16 + l15;
                float v = acc[mi][ni][r];
                if (MODE == 0) {
                    Cf[(size_t)row * N + col] = v;
                } else if (MODE == 1) {
                    Cb[(size_t)row * N + col] = (bf16_t)v;
                } else {
                    int h = col >> 8, dd = col & 255;
                    if (dd < 128)
                        knope[((size_t)h * T_TOK + row) * 128 + dd] = (bf16_t)v;
                    else
                        vtmp[(size_t)row * 2048 + h * 128 + (dd - 128)] = (bf16_t)v;
                }
            }
}

// ---------------------------------------------------------------------------
// fp32 [K][N] -> bf16 [N][K] transpose+convert (all dims multiples of 32)
// ---------------------------------------------------------------------------
__global__ void transpose_f2b(const float* __restrict__ in, bf16_t* __restrict__ out,
                              int K, int N) {
    __shared__ float tile[32][33];
    int n0 = blockIdx.x * 32, k0 = blockIdx.y * 32;
    int tx = threadIdx.x, ty = threadIdx.y;
    for (int i = ty; i < 32; i += 8)
        tile[i][tx] = in[(size_t)(k0 + i) * N + n0 + tx];
    __syncthreads();
    for (int i = ty; i < 32; i += 8)
        out[(size_t)(n0 + i) * K + k0 + tx] = (bf16_t)tile[tx][i];
}

// bf16 [R][C] -> bf16 [C][R]
__global__ void transpose_b2b(const bf16_t* __restrict__ in, bf16_t* __restrict__ out,
                              int R, int C) {
    __shared__ bf16_t tile[32][33];
    int c0 = blockIdx.x * 32, r0 = blockIdx.y * 32;
    int tx = threadIdx.x, ty = threadIdx.y;
    for (int i = ty; i < 32; i += 8)
        tile[i][tx] = in[(size_t)(r0 + i) * C + c0 + tx];
    __syncthreads();
    for (int i = ty; i < 32; i += 8)
        out[(size_t)(c0 + i) * R + r0 + tx] = tile[tx][i];
}

__global__ void cvt_f2b(const float* __restrict__ in, bf16_t* __restrict__ out, int n) {
    int i = blockIdx.x * 256 + threadIdx.x;
    if (i < n) out[i] = (bf16_t)in[i];
}

// ---------------------------------------------------------------------------
// RMSNorm scales (qkv_a padded stride 2176)
// ---------------------------------------------------------------------------
__global__ void rms_scales(const float* __restrict__ qkv_a,
                           float* __restrict__ rq, float* __restrict__ rkv) {
    int row = blockIdx.x, tid = threadIdx.x;
    const float* x = qkv_a + (size_t)row * QKV_NPAD;
    __shared__ float red[256];
    float ss = 0.f;
    for (int c = tid; c < Q_LORA; c += 256) { float v = x[c]; ss += v * v; }
    red[tid] = ss;
    __syncthreads();
    for (int o = 128; o > 0; o >>= 1) {
        if (tid < o) red[tid] += red[tid + o];
        __syncthreads();
    }
    if (tid == 0) rq[row] = rsqrtf(red[0] / (float)Q_LORA + 1e-6f);
    __syncthreads();
    ss = 0.f;
    for (int c = Q_LORA + tid; c < Q_LORA + KV_LORA; c += 256) { float v = x[c]; ss += v * v; }
    red[tid] = ss;
    __syncthreads();
    for (int o = 128; o > 0; o >>= 1) {
        if (tid < o) red[tid] += red[tid + o];
        __syncthreads();
    }
    if (tid == 0) rkv[row] = rsqrtf(red[0] / (float)KV_LORA + 1e-6f);
}

// apply rmsnorm + gain, cast to bf16 GEMM-A operands
__global__ void rms_apply(const float* __restrict__ qkv_a,
                          const float* __restrict__ rq, const float* __restrict__ rkv,
                          const float* __restrict__ g_q, const float* __restrict__ g_kv,
                          bf16_t* __restrict__ qn, bf16_t* __restrict__ kvn) {
    int t = blockIdx.x;
    float a = rq[t], b = rkv[t];
    const float* row = qkv_a + (size_t)t * QKV_NPAD;
    for (int c = threadIdx.x; c < Q_LORA; c += 256)
        qn[(size_t)t * Q_LORA + c] = (bf16_t)(row[c] * a * g_q[c]);
    for (int c = threadIdx.x; c < KV_LORA; c += 256)
        kvn[(size_t)t * KV_LORA + c] = (bf16_t)(row[Q_LORA + c] * b * g_kv[c]);
}

// ---------------------------------------------------------------------------
// RoPE kernels
// ---------------------------------------------------------------------------
__global__ void rope_kpe_kernel(const float* __restrict__ qkv_a,
                                const int* __restrict__ pos, bf16_t* __restrict__ kpe) {
    int idx = blockIdx.x * blockDim.x + threadIdx.x;
    if (idx >= T_TOK * 32) return;
    int t = idx >> 5, i = idx & 31;
    double inv = pow(10000.0, -(double)(2 * i) / 64.0);
    double fd = (double)pos[t] * inv;
    float c = (float)cos(fd), s = (float)sin(fd);
    const float* src = qkv_a + (size_t)t * QKV_NPAD + Q_LORA + KV_LORA;
    float x1 = src[2 * i], x2 = src[2 * i + 1];
    kpe[t * 64 + 2 * i] = (bf16_t)(x1 * c - x2 * s);
    kpe[t * 64 + 2 * i + 1] = (bf16_t)(x1 * s + x2 * c);
}

__global__ void rope_q_kernel(bf16_t* __restrict__ q, const int* __restrict__ pos) {
    int idx = blockIdx.x * blockDim.x + threadIdx.x;
    if (idx >= T_TOK * NH * 32) return;
    int i = idx & 31;
    int h = (idx >> 5) & (NH - 1);
    int t = idx >> 9;
    double inv = pow(10000.0, -(double)(2 * i) / 64.0);
    double fd = (double)pos[t] * inv;
    float c = (float)cos(fd), s = (float)sin(fd);
    bf16_t* base = q + (size_t)t * (NH * D_QK) + h * D_QK + D_NOPE;
    float x1 = (float)base[2 * i], x2 = (float)base[2 * i + 1];
    base[2 * i] = (bf16_t)(x1 * c - x2 * s);
    base[2 * i + 1] = (bf16_t)(x1 * s + x2 * c);
}

// ---------------------------------------------------------------------------
// MFMA flash attention. Block = (q-tile of 64, head). 4 waves, each owns a
// 16-query strip. K-tiles of 64 staged via global_load_lds in [kstep][row][32]
// sub-tile layouts (64B rows). Online softmax in registers per 16-lane group.
// P goes through LDS (pad 72) to convert C-layout -> A-layout (m120 pattern).
//   qbuf : [T][NH*192] bf16 (rope applied)
//   knope: [NH][T][128] bf16
//   kpe  : [T][64]      bf16 (shared across heads)
//   vT   : [NH][128][T] bf16
//   attn_o:[T][NH*128]  bf16
// ---------------------------------------------------------------------------
__global__ __launch_bounds__(256) void attn_mfma(
    const bf16_t* __restrict__ qbuf, const bf16_t* __restrict__ knope,
    const bf16_t* __restrict__ kpe, const bf16_t* __restrict__ vT,
    bf16_t* __restrict__ attn_o)
{
    const int h = blockIdx.y;
    const int qt = 31 - blockIdx.x;          // big q-tiles dispatch first
    const int q0 = qt * 64;
    const int tid = threadIdx.x, lane = tid & 63, w = tid >> 6;
    const int l15 = lane & 15, quad = lane >> 4;

    __shared__ __align__(16) bf16_t kn2[4 * 64 * 32];   // [kk][s][32]
    __shared__ __align__(16) bf16_t kp2[2 * 64 * 32];   // [kk][s][32]
    __shared__ __align__(16) bf16_t vt2[2 * 128 * 32];  // [ks][d][32]
    __shared__ __align__(16) bf16_t p_s[64 * 72];       // [q][72] (pad kills 16-way)

    // Q fragments held in registers (one strip per wave): 4 nope + 2 pe k-steps
    bf16x8 qf[6];
    {
        const bf16_t* qp = qbuf + (size_t)(q0 + w * 16 + l15) * (NH * D_QK) + h * D_QK;
#pragma unroll
        for (int kk = 0; kk < 6; ++kk)
            qf[kk] = *(const bf16x8*)(qp + kk * 32 + quad * 8);
    }

    floatx4 o[8] = {};
    float mrow[4], lrow[4];
#pragma unroll
    for (int r = 0; r < 4; ++r) { mrow[r] = -3.0e38f; lrow[r] = 0.f; }

    for (int s0 = 0; s0 <= q0; s0 += 64) {
        // ---- stage K/V tiles (async, lane-linear LDS dests) ----
#pragma unroll
        for (int it = 0; it < 4; ++it) {   // knope: 64 rows x 256B
            int slot = it * 256 + tid;
            int s = (slot >> 2) & 63, c = slot & 3, kk = slot >> 8;
            gload16((const char*)(knope + ((size_t)h * T_TOK + s0 + s) * 128 + kk * 32 + c * 8),
                    (char*)kn2 + slot * 16);
        }
#pragma unroll
        for (int it = 0; it < 2; ++it) {   // kpe: 64 rows x 128B
            int slot = it * 256 + tid;
            int s = (slot >> 2) & 63, c = slot & 3, kk = slot >> 8;
            gload16((const char*)(kpe + (size_t)(s0 + s) * 64 + kk * 32 + c * 8),
                    (char*)kp2 + slot * 16);
        }
#pragma unroll
        for (int it = 0; it < 4; ++it) {   // vT: 128 rows x 128B
            int slot = it * 256 + tid;
            int d = (slot >> 2) & 127, c = slot & 3, ks = slot >> 9;
            gload16((const char*)(vT + ((size_t)h * 128 + d) * T_TOK + s0 + ks * 32 + c * 8),
                    (char*)vt2 + slot * 16);
        }
        __syncthreads();

        // ---- S = Q K^T for this wave's 16 rows x 64 cols ----
        floatx4 s_acc[4] = {};
#pragma unroll
        for (int ni = 0; ni < 4; ++ni) {
#pragma unroll
            for (int kk = 0; kk < 4; ++kk) {
                bf16x8 b = *(const bf16x8*)(kn2 + (kk * 64 + ni * 16 + l15) * 32 + quad * 8);
                s_acc[ni] = MFMA_BF16(qf[kk], b, s_acc[ni]);
            }
#pragma unroll
            for (int kk = 0; kk < 2; ++kk) {
                bf16x8 b = *(const bf16x8*)(kp2 + (kk * 64 + ni * 16 + l15) * 32 + quad * 8);
                s_acc[ni] = MFMA_BF16(qf[4 + kk], b, s_acc[ni]);
            }
        }

        const bool diag = (s0 == q0);
#pragma unroll
        for (int ni = 0; ni < 4; ++ni)
#pragma unroll
            for (int r = 0; r < 4; ++r) {
                float v = s_acc[ni][r] * SCALING;
                if (diag && (ni * 16 + l15) > (w * 16 + quad * 4 + r)) v = -3.0e38f;
                s_acc[ni][r] = v;
            }

        // ---- online softmax (rows live in 16-lane groups; xor-reduce) ----
        float alpha[4], tsum[4];
#pragma unroll
        for (int r = 0; r < 4; ++r) {
            float mx = fmaxf(fmaxf(s_acc[0][r], s_acc[1][r]),
                             fmaxf(s_acc[2][r], s_acc[3][r]));
            mx = fmaxf(mx, __shfl_xor(mx, 1, 64));
            mx = fmaxf(mx, __shfl_xor(mx, 2, 64));
            mx = fmaxf(mx, __shfl_xor(mx, 4, 64));
            mx = fmaxf(mx, __shfl_xor(mx, 8, 64));
            float mnew = fmaxf(mrow[r], mx);
            alpha[r] = exp2f((mrow[r] - mnew) * LOG2E);
            mrow[r] = mnew;
            tsum[r] = 0.f;
        }
#pragma unroll
        for (int ni = 0; ni < 4; ++ni)
#pragma unroll
            for (int r = 0; r < 4; ++r) {
                float p = exp2f((s_acc[ni][r] - mrow[r]) * LOG2E);
                tsum[r] += p;
                p_s[(w * 16 + quad * 4 + r) * 72 + ni * 16 + l15] = (bf16_t)p;
            }
#pragma unroll
        for (int r = 0; r < 4; ++r) {
            float s = tsum[r];
            s += __shfl_xor(s, 1, 64);
            s += __shfl_xor(s, 2, 64);
            s += __shfl_xor(s, 4, 64);
            s += __shfl_xor(s, 8, 64);
            lrow[r] = lrow[r] * alpha[r] + s;
        }
#pragma unroll
        for (int ni = 0; ni < 8; ++ni)
#pragma unroll
            for (int r = 0; r < 4; ++r) o[ni][r] *= alpha[r];

        // ---- O += P V  (P rows are this wave's own; no barrier needed) ----
#pragma unroll
        for (int ks = 0; ks < 2; ++ks) {
            bf16x8 a = *(const bf16x8*)(p_s + (w * 16 + l15) * 72 + ks * 32 + quad * 8);
#pragma unroll
            for (int ni = 0; ni < 8; ++ni) {
                bf16x8 b = *(const bf16x8*)(vt2 + (ks * 128 + ni * 16 + l15) * 32 + quad * 8);
                o[ni] = MFMA_BF16(a, b, o[ni]);
            }
        }
        __syncthreads();
    }

#pragma unroll
    for (int ni = 0; ni < 8; ++ni)
#pragma unroll
        for (int r = 0; r < 4; ++r) {
            int row = q0 + w * 16 + quad * 4 + r;
            int col = h * 128 + ni * 16 + l15;
            attn_o[(size_t)row * (NH * D_V) + col] = (bf16_t)(o[ni][r] / lrow[r]);
        }
}

// ---------------------------------------------------------------------------
extern "C" void kernel_launch(void* const* d_in, const int* in_sizes, int n_in,
                              void* d_out, int out_size, void* d_ws, size_t ws_size,
                              hipStream_t stream) {
    const float* hidden = (const float*)d_in[0];
    const int* positions = (const int*)d_in[1];
    const float* w_qkv_a = (const float*)d_in[2];
    const float* g_q = (const float*)d_in[3];
    const float* w_q_b = (const float*)d_in[4];
    const float* g_kv = (const float*)d_in[5];
    const float* w_kv_b = (const float*)d_in[6];
    const float* w_o = (const float*)d_in[7];
    float* out = (float*)d_out;

    // ---- workspace layout (~95.2 MB) ----
    char* p = (char*)d_ws;
    float* qkv_a = (float*)p;                       // [2048][2176] fp32
    bf16_t* attn_o = (bf16_t*)p;                    // alias (qkv_a dead by then)
    p += (size_t)T_TOK * QKV_NPAD * 4;
    bf16_t* hbf = (bf16_t*)p;                       // [2048][2048] bf16
    bf16_t* qn = hbf;                               // alias after GEMM1: [2048][1536]
    bf16_t* kvn = hbf + (size_t)T_TOK * Q_LORA;     // [2048][512]
    p += (size_t)T_TOK * HID * 2;
    bf16_t* qbuf = (bf16_t*)p;  p += (size_t)T_TOK * NH * D_QK * 2;   // [2048][3072]
    bf16_t* vtmp = (bf16_t*)p;  p += (size_t)T_TOK * NH * D_V * 2;    // [2048][2048]
    bf16_t* knope = (bf16_t*)p; p += (size_t)NH * T_TOK * 128 * 2;    // [16][2048][128]
    bf16_t* vT = (bf16_t*)p;    p += (size_t)NH * 128 * T_TOK * 2;    // [16][128][2048]
    bf16_t* kpe = (bf16_t*)p;   p += (size_t)T_TOK * 64 * 2;          // [2048][64]
    float* rq = (float*)p;      p += T_TOK * 4;
    float* rkv = (float*)p;     p += T_TOK * 4;
    bf16_t* wt_qkv_a = (bf16_t*)p; p += (size_t)QKV_NPAD * HID * 2;   // [2176][2048]
    bf16_t* wt_q_b = (bf16_t*)p;   p += (size_t)3072 * Q_LORA * 2;    // [3072][1536]
    bf16_t* wt_kv_b = (bf16_t*)p;  p += (size_t)4096 * KV_LORA * 2;   // [4096][512]
    bf16_t* wt_o = (bf16_t*)p;                                        // [2048][2048]

    dim3 tb(32, 8);

    // 0. dtype prep: hidden->bf16; weights -> bf16 transposed [N][K]
    cvt_f2b<<<(T_TOK * HID) / 256, 256, 0, stream>>>(hidden, hbf, T_TOK * HID);
    transpose_f2b<<<dim3(QKV_N / 32, HID / 32), tb, 0, stream>>>(w_qkv_a, wt_qkv_a, HID, QKV_N);
    transpose_f2b<<<dim3(3072 / 32, Q_LORA / 32), tb, 0, stream>>>(w_q_b, wt_q_b, Q_LORA, 3072);
    transpose_f2b<<<dim3(4096 / 32, KV_LORA / 32), tb, 0, stream>>>(w_kv_b, wt_kv_b, KV_LORA, 4096);
    transpose_f2b<<<dim3(HID / 32, HID / 32), tb, 0, stream>>>(w_o, wt_o, HID, HID);

    // 1. qkv_a = hidden @ w_qkv_a   (N padded to 2176; pad cols never read)
    gemm_mfma<0><<<dim3(QKV_NPAD / 128, T_TOK / 128), 256, 0, stream>>>(
        hbf, wt_qkv_a, qkv_a, nullptr, nullptr, nullptr, T_TOK, QKV_NPAD, HID);

    // 2. rmsnorm scales + rope(k_pe) + normalized bf16 A-operands
    rms_scales<<<T_TOK, 256, 0, stream>>>(qkv_a, rq, rkv);
    rope_kpe_kernel<<<(T_TOK * 32) / 256, 256, 0, stream>>>(qkv_a, positions, kpe);
    rms_apply<<<T_TOK, 256, 0, stream>>>(qkv_a, rq, rkv, g_q, g_kv, qn, kvn);

    // 3. q = qn @ w_q_b ; rope in place
    gemm_mfma<1><<<dim3(3072 / 128, T_TOK / 128), 256, 0, stream>>>(
        qn, wt_q_b, nullptr, qbuf, nullptr, nullptr, T_TOK, 3072, Q_LORA);
    rope_q_kernel<<<(T_TOK * NH * 32) / 256, 256, 0, stream>>>(qbuf, positions);

    // 4. kv = kvn @ w_kv_b with split epilogue -> knope + vtmp; then vtmp -> vT
    gemm_mfma<2><<<dim3(4096 / 128, T_TOK / 128), 256, 0, stream>>>(
        kvn, wt_kv_b, nullptr, nullptr, knope, vtmp, T_TOK, 4096, KV_LORA);
    transpose_b2b<<<dim3(HID / 32, T_TOK / 32), tb, 0, stream>>>(vtmp, vT, T_TOK, HID);

    // 5. flash attention (writes attn_o over dead qkv_a)
    attn_mfma<<<dim3(32, NH), 256, 0, stream>>>(qbuf, knope, kpe, vT, attn_o);

    // 6. out = attn_o @ w_o
    gemm_mfma<0><<<dim3(HID / 128, T_TOK / 128), 256, 0, stream>>>(
        attn_o, wt_o, out, nullptr, nullptr, nullptr, T_TOK, HID, NH * D_V);
}

// Round 5
// 431.247 us; speedup vs baseline: 23.6353x; 1.1617x over previous
//
#include <hip/hip_runtime.h>
#include <hip/hip_bf16.h>
#include <math.h>

typedef __bf16 bf16_t;
typedef __bf16 bf16x8 __attribute__((ext_vector_type(8)));
typedef float floatx4 __attribute__((ext_vector_type(4)));

#define T_TOK 2048
#define HID 2048
#define NH 16
#define D_NOPE 128
#define D_ROPE 64
#define D_QK 192
#define D_V 128
#define Q_LORA 1536
#define KV_LORA 512
#define QKV_N 2112            // 1536+512+64
#define QKV_NPAD 2176         // padded to 17*128
#define SCALING 0.07216878364870323f
#define LOG2E 1.442695041f

#define MFMA_BF16(a, b, c) __builtin_amdgcn_mfma_f32_16x16x32_bf16(a, b, c, 0, 0, 0)

// async 16B global->LDS (verified m97 pattern; LDS dest must be lane-linear)
__device__ __forceinline__ void gload16(const void* g, void* l) {
    __builtin_amdgcn_global_load_lds(
        (const __attribute__((address_space(1))) unsigned int*)g,
        (__attribute__((address_space(3))) unsigned int*)l, 16, 0, 0);
}

// ---------------------------------------------------------------------------
// m97-style MFMA GEMM: C[M,N] = A[M,K] * Bt[N,K]^T, 128x128 tile, BK=32.
// (unchanged from round 4 — correct, ~500 TF class)
// ---------------------------------------------------------------------------
template <int MODE>
__global__ __launch_bounds__(256) void gemm_mfma(
    const bf16_t* __restrict__ A, const bf16_t* __restrict__ Bt,
    float* __restrict__ Cf, bf16_t* __restrict__ Cb,
    bf16_t* __restrict__ knope, bf16_t* __restrict__ vtmp,
    int M, int N, int K)
{
    __shared__ __align__(16) bf16_t As[128 * 32];
    __shared__ __align__(16) bf16_t Bs[128 * 32];
    const int tid = threadIdx.x;
    const int lane = tid & 63;
    const int w = tid >> 6;
    const int wm = w >> 1, wn = w & 1;
    const int m0 = blockIdx.y * 128, n0 = blockIdx.x * 128;
    const int l15 = lane & 15, quad = lane >> 4;

    floatx4 acc[4][4] = {};

    for (int k0 = 0; k0 < K; k0 += 32) {
#pragma unroll
        for (int it = 0; it < 2; ++it) {
            int slot = it * 256 + tid;
            int row = slot >> 2, cb = (slot & 3) * 16;
            gload16((const char*)(A + (size_t)(m0 + row) * K + k0) + cb,
                    (char*)As + slot * 16);
            gload16((const char*)(Bt + (size_t)(n0 + row) * K + k0) + cb,
                    (char*)Bs + slot * 16);
        }
        __syncthreads();
        bf16x8 af[4], bfr[4];
#pragma unroll
        for (int mi = 0; mi < 4; ++mi)
            af[mi] = *(const bf16x8*)(As + (wm * 64 + mi * 16 + l15) * 32 + quad * 8);
#pragma unroll
        for (int ni = 0; ni < 4; ++ni)
            bfr[ni] = *(const bf16x8*)(Bs + (wn * 64 + ni * 16 + l15) * 32 + quad * 8);
#pragma unroll
        for (int mi = 0; mi < 4; ++mi)
#pragma unroll
            for (int ni = 0; ni < 4; ++ni)
                acc[mi][ni] = MFMA_BF16(af[mi], bfr[ni], acc[mi][ni]);
        __syncthreads();
    }

#pragma unroll
    for (int mi = 0; mi < 4; ++mi)
#pragma unroll
        for (int ni = 0; ni < 4; ++ni)
#pragma unroll
            for (int r = 0; r < 4; ++r) {
                int row = m0 + wm * 64 + mi * 16 + quad * 4 + r;
                int col = n0 + wn * 64 + ni * 16 + l15;
                float v = acc[mi][ni][r];
                if (MODE == 0) {
                    Cf[(size_t)row * N + col] = v;
                } else if (MODE == 1) {
                    Cb[(size_t)row * N + col] = (bf16_t)v;
                } else {
                    int h = col >> 8, dd = col & 255;
                    if (dd < 128)
                        knope[((size_t)h * T_TOK + row) * 128 + dd] = (bf16_t)v;
                    else
                        vtmp[(size_t)row * 2048 + h * 128 + (dd - 128)] = (bf16_t)v;
                }
            }
}

// ---------------------------------------------------------------------------
// transposes / converts (unchanged)
// ---------------------------------------------------------------------------
__global__ void transpose_f2b(const float* __restrict__ in, bf16_t* __restrict__ out,
                              int K, int N) {
    __shared__ float tile[32][33];
    int n0 = blockIdx.x * 32, k0 = blockIdx.y * 32;
    int tx = threadIdx.x, ty = threadIdx.y;
    for (int i = ty; i < 32; i += 8)
        tile[i][tx] = in[(size_t)(k0 + i) * N + n0 + tx];
    __syncthreads();
    for (int i = ty; i < 32; i += 8)
        out[(size_t)(n0 + i) * K + k0 + tx] = (bf16_t)tile[tx][i];
}

__global__ void transpose_b2b(const bf16_t* __restrict__ in, bf16_t* __restrict__ out,
                              int R, int C) {
    __shared__ bf16_t tile[32][33];
    int c0 = blockIdx.x * 32, r0 = blockIdx.y * 32;
    int tx = threadIdx.x, ty = threadIdx.y;
    for (int i = ty; i < 32; i += 8)
        tile[i][tx] = in[(size_t)(r0 + i) * C + c0 + tx];
    __syncthreads();
    for (int i = ty; i < 32; i += 8)
        out[(size_t)(c0 + i) * R + r0 + tx] = tile[tx][i];
}

__global__ void cvt_f2b(const float* __restrict__ in, bf16_t* __restrict__ out, int n) {
    int i = blockIdx.x * 256 + threadIdx.x;
    if (i < n) out[i] = (bf16_t)in[i];
}

// ---------------------------------------------------------------------------
// RMSNorm scales / apply / RoPE (unchanged)
// ---------------------------------------------------------------------------
__global__ void rms_scales(const float* __restrict__ qkv_a,
                           float* __restrict__ rq, float* __restrict__ rkv) {
    int row = blockIdx.x, tid = threadIdx.x;
    const float* x = qkv_a + (size_t)row * QKV_NPAD;
    __shared__ float red[256];
    float ss = 0.f;
    for (int c = tid; c < Q_LORA; c += 256) { float v = x[c]; ss += v * v; }
    red[tid] = ss;
    __syncthreads();
    for (int o = 128; o > 0; o >>= 1) {
        if (tid < o) red[tid] += red[tid + o];
        __syncthreads();
    }
    if (tid == 0) rq[row] = rsqrtf(red[0] / (float)Q_LORA + 1e-6f);
    __syncthreads();
    ss = 0.f;
    for (int c = Q_LORA + tid; c < Q_LORA + KV_LORA; c += 256) { float v = x[c]; ss += v * v; }
    red[tid] = ss;
    __syncthreads();
    for (int o = 128; o > 0; o >>= 1) {
        if (tid < o) red[tid] += red[tid + o];
        __syncthreads();
    }
    if (tid == 0) rkv[row] = rsqrtf(red[0] / (float)KV_LORA + 1e-6f);
}

__global__ void rms_apply(const float* __restrict__ qkv_a,
                          const float* __restrict__ rq, const float* __restrict__ rkv,
                          const float* __restrict__ g_q, const float* __restrict__ g_kv,
                          bf16_t* __restrict__ qn, bf16_t* __restrict__ kvn) {
    int t = blockIdx.x;
    float a = rq[t], b = rkv[t];
    const float* row = qkv_a + (size_t)t * QKV_NPAD;
    for (int c = threadIdx.x; c < Q_LORA; c += 256)
        qn[(size_t)t * Q_LORA + c] = (bf16_t)(row[c] * a * g_q[c]);
    for (int c = threadIdx.x; c < KV_LORA; c += 256)
        kvn[(size_t)t * KV_LORA + c] = (bf16_t)(row[Q_LORA + c] * b * g_kv[c]);
}

__global__ void rope_kpe_kernel(const float* __restrict__ qkv_a,
                                const int* __restrict__ pos, bf16_t* __restrict__ kpe) {
    int idx = blockIdx.x * blockDim.x + threadIdx.x;
    if (idx >= T_TOK * 32) return;
    int t = idx >> 5, i = idx & 31;
    double inv = pow(10000.0, -(double)(2 * i) / 64.0);
    double fd = (double)pos[t] * inv;
    float c = (float)cos(fd), s = (float)sin(fd);
    const float* src = qkv_a + (size_t)t * QKV_NPAD + Q_LORA + KV_LORA;
    float x1 = src[2 * i], x2 = src[2 * i + 1];
    kpe[t * 64 + 2 * i] = (bf16_t)(x1 * c - x2 * s);
    kpe[t * 64 + 2 * i + 1] = (bf16_t)(x1 * s + x2 * c);
}

__global__ void rope_q_kernel(bf16_t* __restrict__ q, const int* __restrict__ pos) {
    int idx = blockIdx.x * blockDim.x + threadIdx.x;
    if (idx >= T_TOK * NH * 32) return;
    int i = idx & 31;
    int h = (idx >> 5) & (NH - 1);
    int t = idx >> 9;
    double inv = pow(10000.0, -(double)(2 * i) / 64.0);
    double fd = (double)pos[t] * inv;
    float c = (float)cos(fd), s = (float)sin(fd);
    bf16_t* base = q + (size_t)t * (NH * D_QK) + h * D_QK + D_NOPE;
    float x1 = (float)base[2 * i], x2 = (float)base[2 * i + 1];
    base[2 * i] = (bf16_t)(x1 * c - x2 * s);
    base[2 * i + 1] = (bf16_t)(x1 * s + x2 * c);
}

// ---------------------------------------------------------------------------
// Flash attention v2: block = (head, pair p) handling q-tiles p and 31-p
// INTERLEAVED over a shared s-loop (33 tile-computes per block — perfectly
// balanced), double-buffered K/V staging, head->XCD L2 locality.
// ---------------------------------------------------------------------------
__device__ __forceinline__ void flash_tile(
    const bf16_t* kn, const bf16_t* kp, const bf16_t* vt, bf16_t* p_s,
    const bf16x8* qf, floatx4* o, float* mrow, float* lrow,
    bool diag, int w, int l15, int quad)
{
    floatx4 s_acc[4] = {};
#pragma unroll
    for (int ni = 0; ni < 4; ++ni) {
#pragma unroll
        for (int kk = 0; kk < 4; ++kk) {
            bf16x8 b = *(const bf16x8*)(kn + (kk * 64 + ni * 16 + l15) * 32 + quad * 8);
            s_acc[ni] = MFMA_BF16(qf[kk], b, s_acc[ni]);
        }
#pragma unroll
        for (int kk = 0; kk < 2; ++kk) {
            bf16x8 b = *(const bf16x8*)(kp + (kk * 64 + ni * 16 + l15) * 32 + quad * 8);
            s_acc[ni] = MFMA_BF16(qf[4 + kk], b, s_acc[ni]);
        }
    }
#pragma unroll
    for (int ni = 0; ni < 4; ++ni)
#pragma unroll
        for (int r = 0; r < 4; ++r) {
            float v = s_acc[ni][r] * SCALING;
            if (diag && (ni * 16 + l15) > (w * 16 + quad * 4 + r)) v = -3.0e38f;
            s_acc[ni][r] = v;
        }

    float alpha[4], tsum[4];
#pragma unroll
    for (int r = 0; r < 4; ++r) {
        float mx = fmaxf(fmaxf(s_acc[0][r], s_acc[1][r]),
                         fmaxf(s_acc[2][r], s_acc[3][r]));
        mx = fmaxf(mx, __shfl_xor(mx, 1, 64));
        mx = fmaxf(mx, __shfl_xor(mx, 2, 64));
        mx = fmaxf(mx, __shfl_xor(mx, 4, 64));
        mx = fmaxf(mx, __shfl_xor(mx, 8, 64));
        float mnew = fmaxf(mrow[r], mx);
        alpha[r] = exp2f((mrow[r] - mnew) * LOG2E);
        mrow[r] = mnew;
        tsum[r] = 0.f;
    }
#pragma unroll
    for (int ni = 0; ni < 4; ++ni)
#pragma unroll
        for (int r = 0; r < 4; ++r) {
            float p = exp2f((s_acc[ni][r] - mrow[r]) * LOG2E);
            tsum[r] += p;
            p_s[(w * 16 + quad * 4 + r) * 72 + ni * 16 + l15] = (bf16_t)p;
        }
#pragma unroll
    for (int r = 0; r < 4; ++r) {
        float s = tsum[r];
        s += __shfl_xor(s, 1, 64);
        s += __shfl_xor(s, 2, 64);
        s += __shfl_xor(s, 4, 64);
        s += __shfl_xor(s, 8, 64);
        lrow[r] = lrow[r] * alpha[r] + s;
    }
#pragma unroll
    for (int ni = 0; ni < 8; ++ni)
#pragma unroll
        for (int r = 0; r < 4; ++r) o[ni][r] *= alpha[r];

    // O += P V (wave-private rows of p_s; no barrier needed)
#pragma unroll
    for (int ks = 0; ks < 2; ++ks) {
        bf16x8 a = *(const bf16x8*)(p_s + (w * 16 + l15) * 72 + ks * 32 + quad * 8);
#pragma unroll
        for (int ni = 0; ni < 8; ++ni) {
            bf16x8 b = *(const bf16x8*)(vt + (ks * 128 + ni * 16 + l15) * 32 + quad * 8);
            o[ni] = MFMA_BF16(a, b, o[ni]);
        }
    }
}

__global__ __launch_bounds__(256, 1) void attn_mfma(
    const bf16_t* __restrict__ qbuf, const bf16_t* __restrict__ knope,
    const bf16_t* __restrict__ kpe, const bf16_t* __restrict__ vT,
    bf16_t* __restrict__ attn_o)
{
    const int h = blockIdx.x;                 // linear id = p*NH + h -> id%8 = h%8 (XCD locality)
    const int p = blockIdx.y;                 // pair index 0..15
    const int qtA = p, qtB = 31 - p;
    const int q0A = qtA * 64, q0B = qtB * 64;
    const int tid = threadIdx.x, lane = tid & 63, w = tid >> 6;
    const int l15 = lane & 15, quad = lane >> 4;

    __shared__ __align__(16) bf16_t kn2[2][4 * 64 * 32];   // 2 x 16 KB
    __shared__ __align__(16) bf16_t kp2[2][2 * 64 * 32];   // 2 x  8 KB
    __shared__ __align__(16) bf16_t vt2[2][2 * 128 * 32];  // 2 x 16 KB
    __shared__ __align__(16) bf16_t p_s[64 * 72];          // 9 KB

    // Q fragments for both tiles (wave w owns rows [q0+w*16, q0+w*16+16))
    bf16x8 qfA[6], qfB[6];
    {
        const bf16_t* qa = qbuf + (size_t)(q0A + w * 16 + l15) * (NH * D_QK) + h * D_QK;
        const bf16_t* qb = qbuf + (size_t)(q0B + w * 16 + l15) * (NH * D_QK) + h * D_QK;
#pragma unroll
        for (int kk = 0; kk < 6; ++kk) {
            qfA[kk] = *(const bf16x8*)(qa + kk * 32 + quad * 8);
            qfB[kk] = *(const bf16x8*)(qb + kk * 32 + quad * 8);
        }
    }

    floatx4 oA[8] = {}, oB[8] = {};
    float mA[4], lA[4], mB[4], lB[4];
#pragma unroll
    for (int r = 0; r < 4; ++r) { mA[r] = mB[r] = -3.0e38f; lA[r] = lB[r] = 0.f; }

    const int nIter = qtB + 1;   // 17..32; compute work = 33 tile-computes for all p

    // ---- staging helper (lane-linear LDS dests per wave) ----
#define STAGE(buf, s0)                                                                   \
    do {                                                                                 \
        _Pragma("unroll")                                                                \
        for (int it = 0; it < 4; ++it) {                                                 \
            int slot = it * 256 + tid;                                                   \
            int s = (slot >> 2) & 63, c = slot & 3, kk = slot >> 8;                      \
            gload16((const char*)(knope + ((size_t)h * T_TOK + (s0) + s) * 128 +         \
                                  kk * 32 + c * 8),                                      \
                    (char*)kn2[buf] + slot * 16);                                        \
        }                                                                                \
        _Pragma("unroll")                                                                \
        for (int it = 0; it < 2; ++it) {                                                 \
            int slot = it * 256 + tid;                                                   \
            int s = (slot >> 2) & 63, c = slot & 3, kk = slot >> 8;                      \
            gload16((const char*)(kpe + (size_t)((s0) + s) * 64 + kk * 32 + c * 8),      \
                    (char*)kp2[buf] + slot * 16);                                        \
        }                                                                                \
        _Pragma("unroll")                                                                \
        for (int it = 0; it < 4; ++it) {                                                 \
            int slot = it * 256 + tid;                                                   \
            int d = (slot >> 2) & 127, c = slot & 3, ks = slot >> 9;                     \
            gload16((const char*)(vT + ((size_t)h * 128 + d) * T_TOK + (s0) +            \
                                  ks * 32 + c * 8),                                      \
                    (char*)vt2[buf] + slot * 16);                                        \
        }                                                                                \
    } while (0)

    STAGE(0, 0);

    for (int it = 0; it < nIter; ++it) {
        const int s0 = it * 64;
        const int buf = it & 1;
        __syncthreads();                    // drains tile-it loads (+ frees other buf)
        if (it + 1 < nIter) STAGE(buf ^ 1, s0 + 64);   // prefetch overlaps compute

        // tile B always active
        flash_tile(kn2[buf], kp2[buf], vt2[buf], p_s, qfB, oB, mB, lB,
                   s0 == q0B, w, l15, quad);
        // tile A active while s0 <= q0A (wave-uniform branch)
        if (s0 <= q0A)
            flash_tile(kn2[buf], kp2[buf], vt2[buf], p_s, qfA, oA, mA, lA,
                       s0 == q0A, w, l15, quad);
    }

#pragma unroll
    for (int ni = 0; ni < 8; ++ni)
#pragma unroll
        for (int r = 0; r < 4; ++r) {
            int col = h * 128 + ni * 16 + l15;
            int rowA = q0A + w * 16 + quad * 4 + r;
            int rowB = q0B + w * 16 + quad * 4 + r;
            attn_o[(size_t)rowA * (NH * D_V) + col] = (bf16_t)(oA[ni][r] / lA[r]);
            attn_o[(size_t)rowB * (NH * D_V) + col] = (bf16_t)(oB[ni][r] / lB[r]);
        }
#undef STAGE
}

// ---------------------------------------------------------------------------
extern "C" void kernel_launch(void* const* d_in, const int* in_sizes, int n_in,
                              void* d_out, int out_size, void* d_ws, size_t ws_size,
                              hipStream_t stream) {
    const float* hidden = (const float*)d_in[0];
    const int* positions = (const int*)d_in[1];
    const float* w_qkv_a = (const float*)d_in[2];
    const float* g_q = (const float*)d_in[3];
    const float* w_q_b = (const float*)d_in[4];
    const float* g_kv = (const float*)d_in[5];
    const float* w_kv_b = (const float*)d_in[6];
    const float* w_o = (const float*)d_in[7];
    float* out = (float*)d_out;

    // ---- workspace layout (~95.2 MB) ----
    char* p = (char*)d_ws;
    float* qkv_a = (float*)p;                       // [2048][2176] fp32
    bf16_t* attn_o = (bf16_t*)p;                    // alias (qkv_a dead by then)
    p += (size_t)T_TOK * QKV_NPAD * 4;
    bf16_t* hbf = (bf16_t*)p;                       // [2048][2048] bf16
    bf16_t* qn = hbf;                               // alias after GEMM1: [2048][1536]
    bf16_t* kvn = hbf + (size_t)T_TOK * Q_LORA;     // [2048][512]
    p += (size_t)T_TOK * HID * 2;
    bf16_t* qbuf = (bf16_t*)p;  p += (size_t)T_TOK * NH * D_QK * 2;   // [2048][3072]
    bf16_t* vtmp = (bf16_t*)p;  p += (size_t)T_TOK * NH * D_V * 2;    // [2048][2048]
    bf16_t* knope = (bf16_t*)p; p += (size_t)NH * T_TOK * 128 * 2;    // [16][2048][128]
    bf16_t* vT = (bf16_t*)p;    p += (size_t)NH * 128 * T_TOK * 2;    // [16][128][2048]
    bf16_t* kpe = (bf16_t*)p;   p += (size_t)T_TOK * 64 * 2;          // [2048][64]
    float* rq = (float*)p;      p += T_TOK * 4;
    float* rkv = (float*)p;     p += T_TOK * 4;
    bf16_t* wt_qkv_a = (bf16_t*)p; p += (size_t)QKV_NPAD * HID * 2;   // [2176][2048]
    bf16_t* wt_q_b = (bf16_t*)p;   p += (size_t)3072 * Q_LORA * 2;    // [3072][1536]
    bf16_t* wt_kv_b = (bf16_t*)p;  p += (size_t)4096 * KV_LORA * 2;   // [4096][512]
    bf16_t* wt_o = (bf16_t*)p;                                        // [2048][2048]

    dim3 tb(32, 8);

    // 0. dtype prep: hidden->bf16; weights -> bf16 transposed [N][K]
    cvt_f2b<<<(T_TOK * HID) / 256, 256, 0, stream>>>(hidden, hbf, T_TOK * HID);
    transpose_f2b<<<dim3(QKV_N / 32, HID / 32), tb, 0, stream>>>(w_qkv_a, wt_qkv_a, HID, QKV_N);
    transpose_f2b<<<dim3(3072 / 32, Q_LORA / 32), tb, 0, stream>>>(w_q_b, wt_q_b, Q_LORA, 3072);
    transpose_f2b<<<dim3(4096 / 32, KV_LORA / 32), tb, 0, stream>>>(w_kv_b, wt_kv_b, KV_LORA, 4096);
    transpose_f2b<<<dim3(HID / 32, HID / 32), tb, 0, stream>>>(w_o, wt_o, HID, HID);

    // 1. qkv_a = hidden @ w_qkv_a   (N padded to 2176; pad cols never read)
    gemm_mfma<0><<<dim3(QKV_NPAD / 128, T_TOK / 128), 256, 0, stream>>>(
        hbf, wt_qkv_a, qkv_a, nullptr, nullptr, nullptr, T_TOK, QKV_NPAD, HID);

    // 2. rmsnorm scales + rope(k_pe) + normalized bf16 A-operands
    rms_scales<<<T_TOK, 256, 0, stream>>>(qkv_a, rq, rkv);
    rope_kpe_kernel<<<(T_TOK * 32) / 256, 256, 0, stream>>>(qkv_a, positions, kpe);
    rms_apply<<<T_TOK, 256, 0, stream>>>(qkv_a, rq, rkv, g_q, g_kv, qn, kvn);

    // 3. q = qn @ w_q_b ; rope in place
    gemm_mfma<1><<<dim3(3072 / 128, T_TOK / 128), 256, 0, stream>>>(
        qn, wt_q_b, nullptr, qbuf, nullptr, nullptr, T_TOK, 3072, Q_LORA);
    rope_q_kernel<<<(T_TOK * NH * 32) / 256, 256, 0, stream>>>(qbuf, positions);

    // 4. kv = kvn @ w_kv_b with split epilogue -> knope + vtmp; then vtmp -> vT
    gemm_mfma<2><<<dim3(4096 / 128, T_TOK / 128), 256, 0, stream>>>(
        kvn, wt_kv_b, nullptr, nullptr, knope, vtmp, T_TOK, 4096, KV_LORA);
    transpose_b2b<<<dim3(HID / 32, T_TOK / 32), tb, 0, stream>>>(vtmp, vT, T_TOK, HID);

    // 5. flash attention v2: grid (head, pair) -> id%8 = head%8 (XCD L2 locality)
    attn_mfma<<<dim3(NH, 16), 256, 0, stream>>>(qbuf, knope, kpe, vT, attn_o);

    // 6. out = attn_o @ w_o
    gemm_mfma<0><<<dim3(HID / 128, T_TOK / 128), 256, 0, stream>>>(
        attn_o, wt_o, out, nullptr, nullptr, nullptr, T_TOK, HID, NH * D_V);
}

// Round 6
// 413.475 us; speedup vs baseline: 24.6512x; 1.0430x over previous
//
#include <hip/hip_runtime.h>
#include <hip/hip_bf16.h>
#include <math.h>

typedef __bf16 bf16_t;
typedef __bf16 bf16x8 __attribute__((ext_vector_type(8)));
typedef float floatx4 __attribute__((ext_vector_type(4)));

#define T_TOK 2048
#define HID 2048
#define NH 16
#define D_NOPE 128
#define D_ROPE 64
#define D_QK 192
#define D_V 128
#define Q_LORA 1536
#define KV_LORA 512
#define QKV_N 2112            // 1536+512+64
#define QKV_NPAD 2176         // padded to 17*128
#define SCALING 0.07216878364870323f
#define LOG2E 1.442695041f

#define MFMA_BF16(a, b, c) __builtin_amdgcn_mfma_f32_16x16x32_bf16(a, b, c, 0, 0, 0)

// async 16B global->LDS (verified m97 pattern; LDS dest must be lane-linear)
__device__ __forceinline__ void gload16(const void* g, void* l) {
    __builtin_amdgcn_global_load_lds(
        (const __attribute__((address_space(1))) unsigned int*)g,
        (__attribute__((address_space(3))) unsigned int*)l, 16, 0, 0);
}

// ---------------------------------------------------------------------------
// MFMA GEMM: C[M,N] = A[M,K] * Bt[N,K]^T, 128x128 tile, BK=64 (two 32-k
// sub-tiles per barrier round -> 32 MFMAs/barrier). LDS sub-tile layout
// [kk2][128][32] keeps the 2-way-free bank pattern (m136).
// MODE 0: fp32 C. MODE 1: bf16 C. MODE 2: kv-split epilogue.
// ---------------------------------------------------------------------------
template <int MODE>
__global__ __launch_bounds__(256) void gemm_mfma(
    const bf16_t* __restrict__ A, const bf16_t* __restrict__ Bt,
    float* __restrict__ Cf, bf16_t* __restrict__ Cb,
    bf16_t* __restrict__ knope, bf16_t* __restrict__ vtmp,
    int M, int N, int K)
{
    __shared__ __align__(16) bf16_t As[2 * 128 * 32];   // 16 KB
    __shared__ __align__(16) bf16_t Bs[2 * 128 * 32];   // 16 KB
    const int tid = threadIdx.x;
    const int lane = tid & 63;
    const int w = tid >> 6;
    const int wm = w >> 1, wn = w & 1;
    const int m0 = blockIdx.y * 128, n0 = blockIdx.x * 128;
    const int l15 = lane & 15, quad = lane >> 4;

    floatx4 acc[4][4] = {};

    for (int k0 = 0; k0 < K; k0 += 64) {
#pragma unroll
        for (int it = 0; it < 4; ++it) {
            int slot = it * 256 + tid;                 // 0..1023
            int kk2 = slot >> 9;                       // 0..1
            int r = (slot >> 2) & 127;                 // 0..127
            int c = slot & 3;                          // 0..3 (16B units)
            gload16((const char*)(A + (size_t)(m0 + r) * K + k0 + kk2 * 32 + c * 8),
                    (char*)As + slot * 16);
            gload16((const char*)(Bt + (size_t)(n0 + r) * K + k0 + kk2 * 32 + c * 8),
                    (char*)Bs + slot * 16);
        }
        __syncthreads();
#pragma unroll
        for (int kk2 = 0; kk2 < 2; ++kk2) {
            bf16x8 af[4], bfr[4];
#pragma unroll
            for (int mi = 0; mi < 4; ++mi)
                af[mi] = *(const bf16x8*)(As + kk2 * 4096 +
                                          (wm * 64 + mi * 16 + l15) * 32 + quad * 8);
#pragma unroll
            for (int ni = 0; ni < 4; ++ni)
                bfr[ni] = *(const bf16x8*)(Bs + kk2 * 4096 +
                                           (wn * 64 + ni * 16 + l15) * 32 + quad * 8);
#pragma unroll
            for (int mi = 0; mi < 4; ++mi)
#pragma unroll
                for (int ni = 0; ni < 4; ++ni)
                    acc[mi][ni] = MFMA_BF16(af[mi], bfr[ni], acc[mi][ni]);
        }
        __syncthreads();
    }

#pragma unroll
    for (int mi = 0; mi < 4; ++mi)
#pragma unroll
        for (int ni = 0; ni < 4; ++ni)
#pragma unroll
            for (int r = 0; r < 4; ++r) {
                int row = m0 + wm * 64 + mi * 16 + quad * 4 + r;
                int col = n0 + wn * 64 + ni * 16 + l15;
                float v = acc[mi][ni][r];
                if (MODE == 0) {
                    Cf[(size_t)row * N + col] = v;
                } else if (MODE == 1) {
                    Cb[(size_t)row * N + col] = (bf16_t)v;
                } else {
                    int h = col >> 8, dd = col & 255;
                    if (dd < 128)
                        knope[((size_t)h * T_TOK + row) * 128 + dd] = (bf16_t)v;
                    else
                        vtmp[(size_t)row * 2048 + h * 128 + (dd - 128)] = (bf16_t)v;
                }
            }
}

// ---------------------------------------------------------------------------
// Fused weight prep: all 4 fp32 [K][N] -> bf16 [N][K] transposes in one launch
// ---------------------------------------------------------------------------
__global__ void transpose_all(const float* __restrict__ w0, const float* __restrict__ w1,
                              const float* __restrict__ w2, const float* __restrict__ w3,
                              bf16_t* __restrict__ o0, bf16_t* __restrict__ o1,
                              bf16_t* __restrict__ o2, bf16_t* __restrict__ o3) {
    const float* in; bf16_t* out; int K, N;
    switch (blockIdx.z) {
        case 0: in = w0; out = o0; K = 2048; N = 2112; break;
        case 1: in = w1; out = o1; K = 1536; N = 3072; break;
        case 2: in = w2; out = o2; K = 512;  N = 4096; break;
        default: in = w3; out = o3; K = 2048; N = 2048; break;
    }
    int n0 = blockIdx.x * 32, k0 = blockIdx.y * 32;
    if (n0 >= N || k0 >= K) return;
    __shared__ float tile[32][33];
    int tx = threadIdx.x, ty = threadIdx.y;
    for (int i = ty; i < 32; i += 8)
        tile[i][tx] = in[(size_t)(k0 + i) * N + n0 + tx];
    __syncthreads();
    for (int i = ty; i < 32; i += 8)
        out[(size_t)(n0 + i) * K + k0 + tx] = (bf16_t)tile[tx][i];
}

__global__ void transpose_b2b(const bf16_t* __restrict__ in, bf16_t* __restrict__ out,
                              int R, int C) {
    __shared__ bf16_t tile[32][33];
    int c0 = blockIdx.x * 32, r0 = blockIdx.y * 32;
    int tx = threadIdx.x, ty = threadIdx.y;
    for (int i = ty; i < 32; i += 8)
        tile[i][tx] = in[(size_t)(r0 + i) * C + c0 + tx];
    __syncthreads();
    for (int i = ty; i < 32; i += 8)
        out[(size_t)(c0 + i) * R + r0 + tx] = tile[tx][i];
}

__global__ void cvt_f2b(const float* __restrict__ in, bf16_t* __restrict__ out, int n) {
    int i = blockIdx.x * 256 + threadIdx.x;
    if (i < n) out[i] = (bf16_t)in[i];
}

// ---------------------------------------------------------------------------
// Fused mid-stage: per row -> rms scales (q,kv) + apply gains -> qn/kvn (bf16)
// + rope(k_pe) -> kpe (bf16). One block per token row.
// ---------------------------------------------------------------------------
__global__ void mid_fuse(const float* __restrict__ qkv_a, const int* __restrict__ pos,
                         const float* __restrict__ g_q, const float* __restrict__ g_kv,
                         bf16_t* __restrict__ qn, bf16_t* __restrict__ kvn,
                         bf16_t* __restrict__ kpe) {
    int t = blockIdx.x, tid = threadIdx.x;
    const float* x = qkv_a + (size_t)t * QKV_NPAD;
    __shared__ float red[256];
    float ss = 0.f;
    for (int c = tid; c < Q_LORA; c += 256) { float v = x[c]; ss += v * v; }
    red[tid] = ss;
    __syncthreads();
    for (int o = 128; o > 0; o >>= 1) {
        if (tid < o) red[tid] += red[tid + o];
        __syncthreads();
    }
    float rq = rsqrtf(red[0] / (float)Q_LORA + 1e-6f);
    __syncthreads();
    ss = 0.f;
    for (int c = Q_LORA + tid; c < Q_LORA + KV_LORA; c += 256) { float v = x[c]; ss += v * v; }
    red[tid] = ss;
    __syncthreads();
    for (int o = 128; o > 0; o >>= 1) {
        if (tid < o) red[tid] += red[tid + o];
        __syncthreads();
    }
    float rkv = rsqrtf(red[0] / (float)KV_LORA + 1e-6f);

    for (int c = tid; c < Q_LORA; c += 256)
        qn[(size_t)t * Q_LORA + c] = (bf16_t)(x[c] * rq * g_q[c]);
    for (int c = tid; c < KV_LORA; c += 256)
        kvn[(size_t)t * KV_LORA + c] = (bf16_t)(x[Q_LORA + c] * rkv * g_kv[c]);

    if (tid < 32) {
        int i = tid;
        double inv = pow(10000.0, -(double)(2 * i) / 64.0);
        double fd = (double)pos[t] * inv;
        float c = (float)cos(fd), s = (float)sin(fd);
        float x1 = x[Q_LORA + KV_LORA + 2 * i], x2 = x[Q_LORA + KV_LORA + 2 * i + 1];
        kpe[t * 64 + 2 * i] = (bf16_t)(x1 * c - x2 * s);
        kpe[t * 64 + 2 * i + 1] = (bf16_t)(x1 * s + x2 * c);
    }
}

__global__ void rope_q_kernel(bf16_t* __restrict__ q, const int* __restrict__ pos) {
    int idx = blockIdx.x * blockDim.x + threadIdx.x;
    if (idx >= T_TOK * NH * 32) return;
    int i = idx & 31;
    int h = (idx >> 5) & (NH - 1);
    int t = idx >> 9;
    double inv = pow(10000.0, -(double)(2 * i) / 64.0);
    double fd = (double)pos[t] * inv;
    float c = (float)cos(fd), s = (float)sin(fd);
    bf16_t* base = q + (size_t)t * (NH * D_QK) + h * D_QK + D_NOPE;
    float x1 = (float)base[2 * i], x2 = (float)base[2 * i + 1];
    base[2 * i] = (bf16_t)(x1 * c - x2 * s);
    base[2 * i + 1] = (bf16_t)(x1 * s + x2 * c);
}

// ---------------------------------------------------------------------------
// Flash attention v3: 512 blocks (one 64-row q-tile each), LDS 73 KB ->
// 2 blocks/CU (2 waves/SIMD). kpe B-frags loaded direct from global (L2-hot,
// 256 KB shared by all heads). Dispatch-order pairing: ids 0..255 = short
// tiles 0..15, ids 256..511 = long tiles 31..16 (same head at id, id+256) so
// breadth-first placement balances each CU at 33 iterations.
// ---------------------------------------------------------------------------
__global__ __launch_bounds__(256, 2) void attn_mfma(
    const bf16_t* __restrict__ qbuf, const bf16_t* __restrict__ knope,
    const bf16_t* __restrict__ kpe, const bf16_t* __restrict__ vT,
    bf16_t* __restrict__ attn_o)
{
    const int id = blockIdx.x;
    const int h = id & 15;
    const int g = id >> 4;                    // 0..31
    const int qt = (g < 16) ? g : 47 - g;     // short tiles first, then long
    const int q0 = qt * 64;
    const int tid = threadIdx.x, lane = tid & 63, w = tid >> 6;
    const int l15 = lane & 15, quad = lane >> 4;

    __shared__ __align__(16) bf16_t kn2[2][4 * 64 * 32];   // 32 KB
    __shared__ __align__(16) bf16_t vt2[2][2 * 128 * 32];  // 32 KB
    __shared__ __align__(16) bf16_t p_s[64 * 72];          // 9 KB

    // Q fragments (wave w owns q-rows [q0+w*16, q0+w*16+16))
    bf16x8 qf[6];
    {
        const bf16_t* qp = qbuf + (size_t)(q0 + w * 16 + l15) * (NH * D_QK) + h * D_QK;
#pragma unroll
        for (int kk = 0; kk < 6; ++kk)
            qf[kk] = *(const bf16x8*)(qp + kk * 32 + quad * 8);
    }

    floatx4 o[8] = {};
    float mrow[4], lrow[4];
#pragma unroll
    for (int r = 0; r < 4; ++r) { mrow[r] = -3.0e38f; lrow[r] = 0.f; }

    const int nIter = qt + 1;

#define STAGE(buf, s0)                                                                   \
    do {                                                                                 \
        _Pragma("unroll")                                                                \
        for (int it = 0; it < 4; ++it) {                                                 \
            int slot = it * 256 + tid;                                                   \
            int s = (slot >> 2) & 63, c = slot & 3, kk = slot >> 8;                      \
            gload16((const char*)(knope + ((size_t)h * T_TOK + (s0) + s) * 128 +         \
                                  kk * 32 + c * 8),                                      \
                    (char*)kn2[buf] + slot * 16);                                        \
        }                                                                                \
        _Pragma("unroll")                                                                \
        for (int it = 0; it < 4; ++it) {                                                 \
            int slot = it * 256 + tid;                                                   \
            int d = (slot >> 2) & 127, c = slot & 3, ks = slot >> 9;                     \
            gload16((const char*)(vT + ((size_t)h * 128 + d) * T_TOK + (s0) +            \
                                  ks * 32 + c * 8),                                      \
                    (char*)vt2[buf] + slot * 16);                                        \
        }                                                                                \
    } while (0)

    STAGE(0, 0);

    for (int it = 0; it < nIter; ++it) {
        const int s0 = it * 64;
        const int buf = it & 1;
        __syncthreads();                               // drains this iter's tiles
        if (it + 1 < nIter) STAGE(buf ^ 1, s0 + 64);   // prefetch overlaps compute

        // ---- S = Q K^T (nope from LDS, pe direct from global/L2) ----
        floatx4 s_acc[4] = {};
#pragma unroll
        for (int ni = 0; ni < 4; ++ni) {
#pragma unroll
            for (int kk = 0; kk < 4; ++kk) {
                bf16x8 b = *(const bf16x8*)(kn2[buf] + (kk * 64 + ni * 16 + l15) * 32 + quad * 8);
                s_acc[ni] = MFMA_BF16(qf[kk], b, s_acc[ni]);
            }
#pragma unroll
            for (int kk = 0; kk < 2; ++kk) {
                bf16x8 b = *(const bf16x8*)(kpe + (size_t)(s0 + ni * 16 + l15) * 64 +
                                            kk * 32 + quad * 8);
                s_acc[ni] = MFMA_BF16(qf[4 + kk], b, s_acc[ni]);
            }
        }

        const bool diag = (it == qt);
#pragma unroll
        for (int ni = 0; ni < 4; ++ni)
#pragma unroll
            for (int r = 0; r < 4; ++r) {
                float v = s_acc[ni][r] * SCALING;
                if (diag && (ni * 16 + l15) > (w * 16 + quad * 4 + r)) v = -3.0e38f;
                s_acc[ni][r] = v;
            }

        // ---- online softmax (rows in 16-lane groups) ----
        float alpha[4], tsum[4];
#pragma unroll
        for (int r = 0; r < 4; ++r) {
            float mx = fmaxf(fmaxf(s_acc[0][r], s_acc[1][r]),
                             fmaxf(s_acc[2][r], s_acc[3][r]));
            mx = fmaxf(mx, __shfl_xor(mx, 1, 64));
            mx = fmaxf(mx, __shfl_xor(mx, 2, 64));
            mx = fmaxf(mx, __shfl_xor(mx, 4, 64));
            mx = fmaxf(mx, __shfl_xor(mx, 8, 64));
            float mnew = fmaxf(mrow[r], mx);
            alpha[r] = exp2f((mrow[r] - mnew) * LOG2E);
            mrow[r] = mnew;
            tsum[r] = 0.f;
        }
#pragma unroll
        for (int ni = 0; ni < 4; ++ni)
#pragma unroll
            for (int r = 0; r < 4; ++r) {
                float pv = exp2f((s_acc[ni][r] - mrow[r]) * LOG2E);
                tsum[r] += pv;
                p_s[(w * 16 + quad * 4 + r) * 72 + ni * 16 + l15] = (bf16_t)pv;
            }
#pragma unroll
        for (int r = 0; r < 4; ++r) {
            float s = tsum[r];
            s += __shfl_xor(s, 1, 64);
            s += __shfl_xor(s, 2, 64);
            s += __shfl_xor(s, 4, 64);
            s += __shfl_xor(s, 8, 64);
            lrow[r] = lrow[r] * alpha[r] + s;
        }
#pragma unroll
        for (int ni = 0; ni < 8; ++ni)
#pragma unroll
            for (int r = 0; r < 4; ++r) o[ni][r] *= alpha[r];

        // ---- O += P V (p_s rows wave-private; no barrier) ----
#pragma unroll
        for (int ks = 0; ks < 2; ++ks) {
            bf16x8 a = *(const bf16x8*)(p_s + (w * 16 + l15) * 72 + ks * 32 + quad * 8);
#pragma unroll
            for (int ni = 0; ni < 8; ++ni) {
                bf16x8 b = *(const bf16x8*)(vt2[buf] + (ks * 128 + ni * 16 + l15) * 32 + quad * 8);
                o[ni] = MFMA_BF16(a, b, o[ni]);
            }
        }
    }

#pragma unroll
    for (int ni = 0; ni < 8; ++ni)
#pragma unroll
        for (int r = 0; r < 4; ++r) {
            int row = q0 + w * 16 + quad * 4 + r;
            int col = h * 128 + ni * 16 + l15;
            attn_o[(size_t)row * (NH * D_V) + col] = (bf16_t)(o[ni][r] / lrow[r]);
        }
#undef STAGE
}

// ---------------------------------------------------------------------------
extern "C" void kernel_launch(void* const* d_in, const int* in_sizes, int n_in,
                              void* d_out, int out_size, void* d_ws, size_t ws_size,
                              hipStream_t stream) {
    const float* hidden = (const float*)d_in[0];
    const int* positions = (const int*)d_in[1];
    const float* w_qkv_a = (const float*)d_in[2];
    const float* g_q = (const float*)d_in[3];
    const float* w_q_b = (const float*)d_in[4];
    const float* g_kv = (const float*)d_in[5];
    const float* w_kv_b = (const float*)d_in[6];
    const float* w_o = (const float*)d_in[7];
    float* out = (float*)d_out;

    // ---- workspace layout (~95 MB) ----
    char* p = (char*)d_ws;
    float* qkv_a = (float*)p;                       // [2048][2176] fp32
    bf16_t* attn_o = (bf16_t*)p;                    // alias (qkv_a dead by then)
    p += (size_t)T_TOK * QKV_NPAD * 4;
    bf16_t* hbf = (bf16_t*)p;                       // [2048][2048] bf16
    bf16_t* qn = hbf;                               // alias after GEMM1
    bf16_t* kvn = hbf + (size_t)T_TOK * Q_LORA;
    p += (size_t)T_TOK * HID * 2;
    bf16_t* qbuf = (bf16_t*)p;  p += (size_t)T_TOK * NH * D_QK * 2;   // [2048][3072]
    bf16_t* vtmp = (bf16_t*)p;  p += (size_t)T_TOK * NH * D_V * 2;    // [2048][2048]
    bf16_t* knope = (bf16_t*)p; p += (size_t)NH * T_TOK * 128 * 2;    // [16][2048][128]
    bf16_t* vT = (bf16_t*)p;    p += (size_t)NH * 128 * T_TOK * 2;    // [16][128][2048]
    bf16_t* kpe = (bf16_t*)p;   p += (size_t)T_TOK * 64 * 2;          // [2048][64]
    bf16_t* wt_qkv_a = (bf16_t*)p; p += (size_t)QKV_NPAD * HID * 2;   // [2176][2048]
    bf16_t* wt_q_b = (bf16_t*)p;   p += (size_t)3072 * Q_LORA * 2;    // [3072][1536]
    bf16_t* wt_kv_b = (bf16_t*)p;  p += (size_t)4096 * KV_LORA * 2;   // [4096][512]
    bf16_t* wt_o = (bf16_t*)p;                                        // [2048][2048]

    dim3 tb(32, 8);

    // 0. dtype prep (2 launches)
    cvt_f2b<<<(T_TOK * HID) / 256, 256, 0, stream>>>(hidden, hbf, T_TOK * HID);
    transpose_all<<<dim3(128, 64, 4), tb, 0, stream>>>(
        w_qkv_a, w_q_b, w_kv_b, w_o, wt_qkv_a, wt_q_b, wt_kv_b, wt_o);

    // 1. qkv_a = hidden @ w_qkv_a
    gemm_mfma<0><<<dim3(QKV_NPAD / 128, T_TOK / 128), 256, 0, stream>>>(
        hbf, wt_qkv_a, qkv_a, nullptr, nullptr, nullptr, T_TOK, QKV_NPAD, HID);

    // 2. fused rmsnorm + gains + rope(k_pe)
    mid_fuse<<<T_TOK, 256, 0, stream>>>(qkv_a, positions, g_q, g_kv, qn, kvn, kpe);

    // 3. q = qn @ w_q_b ; rope in place
    gemm_mfma<1><<<dim3(3072 / 128, T_TOK / 128), 256, 0, stream>>>(
        qn, wt_q_b, nullptr, qbuf, nullptr, nullptr, T_TOK, 3072, Q_LORA);
    rope_q_kernel<<<(T_TOK * NH * 32) / 256, 256, 0, stream>>>(qbuf, positions);

    // 4. kv GEMM with split epilogue -> knope + vtmp; vtmp -> vT
    gemm_mfma<2><<<dim3(4096 / 128, T_TOK / 128), 256, 0, stream>>>(
        kvn, wt_kv_b, nullptr, nullptr, knope, vtmp, T_TOK, 4096, KV_LORA);
    transpose_b2b<<<dim3(HID / 32, T_TOK / 32), tb, 0, stream>>>(vtmp, vT, T_TOK, HID);

    // 5. flash attention v3 (512 blocks, 2/CU)
    attn_mfma<<<512, 256, 0, stream>>>(qbuf, knope, kpe, vT, attn_o);

    // 6. out = attn_o @ w_o
    gemm_mfma<0><<<dim3(HID / 128, T_TOK / 128), 256, 0, stream>>>(
        attn_o, wt_o, out, nullptr, nullptr, nullptr, T_TOK, HID, NH * D_V);
}